// Round 9
// baseline (320.795 us; speedup 1.0000x reference)
//
#include <hip/hip_runtime.h>

// Problem constants
constexpr int Bn = 32, Tn = 8, Cn = 1024, Sn = 4096, Hn = 16, HDn = 64;
constexpr int CHUNK = 64, NCHUNK = 64;  // keys per work item
constexpr int PERSIST = 2048;           // persistent 1-wave blocks (8/CU)
constexpr int KSPLIT = 4;               // K-split for the 256x1024x1024 GEMMs
constexpr float SCALE = 0.125f;         // 1/sqrt(64)

// Workspace layout (in floats)
constexpr size_t PROJ_PART = (size_t)Bn * Tn * Cn;          // 262144
constexpr size_t QP_OFF = 0;
constexpr size_t KP_OFF = QP_OFF + KSPLIT * PROJ_PART;
constexpr size_t VP_OFF = KP_OFF + KSPLIT * PROJ_PART;
constexpr size_t PACC_OFF = VP_OFF + KSPLIT * PROJ_PART;
constexpr size_t PACC_SZ = (size_t)NCHUNK * Bn * Hn * Tn * HDn;  // 16.8M floats
constexpr size_t PL_OFF = PACC_OFF + PACC_SZ;
constexpr size_t PL_SZ = (size_t)NCHUNK * Bn * Hn * Tn;
constexpr size_t AW_OFF = PL_OFF + PL_SZ;
constexpr size_t AW_SZ = PROJ_PART;
constexpr size_t OP_OFF = AW_OFF + AW_SZ;
constexpr size_t OP_SZ = (size_t)KSPLIT * PROJ_PART;
constexpr size_t QR_OFF = OP_OFF + OP_SZ;                   // reduced q (pre-scaled)
constexpr size_t KN_OFF = QR_OFF + PROJ_PART;               // reduced k_new
constexpr size_t VN_OFF = KN_OFF + PROJ_PART;               // reduced v_new

typedef __attribute__((address_space(3))) unsigned int lds_uint;
typedef const __attribute__((address_space(1))) unsigned int glb_uint;

__device__ __forceinline__ void gload_lds16(const float* g, float* l) {
    __builtin_amdgcn_global_load_lds((glb_uint*)g, (lds_uint*)l, 16, 0, 0);
}

// ---------------- GEMM: Y_partial[sigma] = X(256xK-slice) @ W^T ----------------
__device__ __forceinline__ void gemm_body(const float* __restrict__ X,
                                          const float* __restrict__ W,
                                          float* __restrict__ Opart,
                                          int sigma, int jblk, int iblk) {
    __shared__ float wl[64][68]; // [k][j], pad 68
    const int tid = threadIdx.x;
    const int c = tid & 15, a = tid >> 4;
    const int j0 = jblk * 64;
    const int ib = iblk * 64 + a * 4;
    const int k0 = sigma * 256;

    float acc[4][4];
#pragma unroll
    for (int ii = 0; ii < 4; ++ii)
#pragma unroll
        for (int jj = 0; jj < 4; ++jj) acc[ii][jj] = 0.f;

    for (int kt = 0; kt < 4; ++kt) {
        const int k1 = k0 + kt * 64;
#pragma unroll
        for (int stp = 0; stp < 4; ++stp) {
            int f4 = stp * 256 + tid;
            int jr = f4 >> 4, e4 = f4 & 15;
            float4 wv = *(const float4*)&W[(size_t)(j0 + jr) * Cn + k1 + e4 * 4];
            wl[e4 * 4 + 0][jr] = wv.x;
            wl[e4 * 4 + 1][jr] = wv.y;
            wl[e4 * 4 + 2][jr] = wv.z;
            wl[e4 * 4 + 3][jr] = wv.w;
        }
        __syncthreads();
#pragma unroll 4
        for (int k4 = 0; k4 < 16; ++k4) {
            float4 xv[4];
#pragma unroll
            for (int ii = 0; ii < 4; ++ii)
                xv[ii] = *(const float4*)&X[(size_t)(ib + ii) * Cn + k1 + k4 * 4];
#pragma unroll
            for (int kk = 0; kk < 4; ++kk) {
                float4 wv = *(const float4*)&wl[k4 * 4 + kk][c * 4];
#pragma unroll
                for (int ii = 0; ii < 4; ++ii) {
                    const float xs = (kk == 0) ? xv[ii].x : (kk == 1) ? xv[ii].y
                                   : (kk == 2) ? xv[ii].z : xv[ii].w;
                    acc[ii][0] += xs * wv.x;
                    acc[ii][1] += xs * wv.y;
                    acc[ii][2] += xs * wv.z;
                    acc[ii][3] += xs * wv.w;
                }
            }
        }
        __syncthreads();
    }
    float* op = Opart + (size_t)sigma * PROJ_PART;
#pragma unroll
    for (int ii = 0; ii < 4; ++ii) {
        float4 o = make_float4(acc[ii][0], acc[ii][1], acc[ii][2], acc[ii][3]);
        *(float4*)&op[(size_t)(ib + ii) * Cn + j0 + c * 4] = o;
    }
}

__global__ __launch_bounds__(256) void proj3_kernel(
    const float* __restrict__ X, const float* __restrict__ W0,
    const float* __restrict__ W1, const float* __restrict__ W2,
    float* __restrict__ O0, float* __restrict__ O1, float* __restrict__ O2) {
    const int z = blockIdx.z;
    const float* W = (z < 4) ? W0 : (z < 8 ? W1 : W2);
    float* O = (z < 4) ? O0 : (z < 8 ? O1 : O2);
    gemm_body(X, W, O, z & 3, blockIdx.x, blockIdx.y);
}

__global__ __launch_bounds__(256) void gemm1_kernel(
    const float* __restrict__ X, const float* __restrict__ W, float* __restrict__ O) {
    gemm_body(X, W, O, blockIdx.z, blockIdx.x, blockIdx.y);
}

// ---------------- Pre-reduce K-split partials -> q (scaled), k_new, v_new ------
__global__ __launch_bounds__(256) void prereduce_kernel(
    const float* __restrict__ qp, const float* __restrict__ kp,
    const float* __restrict__ vp, float* __restrict__ q,
    float* __restrict__ kn, float* __restrict__ vn) {
    const size_t i = ((size_t)blockIdx.x * 256 + threadIdx.x) * 4;
#define SUM4(P)                                                              \
    make_float4(                                                             \
        (*(const float4*)(P + i)).x + (*(const float4*)(P + PROJ_PART + i)).x + \
        (*(const float4*)(P + 2 * PROJ_PART + i)).x + (*(const float4*)(P + 3 * PROJ_PART + i)).x, \
        (*(const float4*)(P + i)).y + (*(const float4*)(P + PROJ_PART + i)).y + \
        (*(const float4*)(P + 2 * PROJ_PART + i)).y + (*(const float4*)(P + 3 * PROJ_PART + i)).y, \
        (*(const float4*)(P + i)).z + (*(const float4*)(P + PROJ_PART + i)).z + \
        (*(const float4*)(P + 2 * PROJ_PART + i)).z + (*(const float4*)(P + 3 * PROJ_PART + i)).z, \
        (*(const float4*)(P + i)).w + (*(const float4*)(P + PROJ_PART + i)).w + \
        (*(const float4*)(P + 2 * PROJ_PART + i)).w + (*(const float4*)(P + 3 * PROJ_PART + i)).w)
    float4 qv = SUM4(qp);
    qv.x *= SCALE; qv.y *= SCALE; qv.z *= SCALE; qv.w *= SCALE;
    *(float4*)&q[i] = qv;
    *(float4*)&kn[i] = SUM4(kp);
    *(float4*)&vn[i] = SUM4(vp);
#undef SUM4
}

// ---------------- Attention partials: persistent 1-wave blocks ----------------
// 2048 persistent single-wave blocks grid-stride over 32768 items (b,cq,h),
// h fastest so the 16 h-partners co-read each 4KB KV row. Per item: 16 K
// gload_lds (swizzled source) + V in 16-row register quarters (software
// pipeline); vmcnt(16) lets QK overlap the V stream. q read via block-uniform
// global loads (scalarizable -> SMEM pipe). LDS 18KB -> 8 blocks/CU =
// 2 waves/SIMD. No barriers anywhere.
__global__ __launch_bounds__(64) void attn_kernel(
    const float* __restrict__ q, const float* __restrict__ kn,
    const float* __restrict__ vn, const float* __restrict__ ck,
    const float* __restrict__ cv, const int* __restrict__ clen,
    float* __restrict__ pacc, float* __restrict__ pl) {
    const int lane = threadIdx.x;
    const int rg = lane >> 4;   // row-in-group 0..3
    const int slot = lane & 15; // 16B column group
    const int swz = lane & 15;

    __shared__ float K_l[64][64]; // 16 KB, XOR-swizzled slots
    __shared__ float p_l[8][64];  // 2 KB, [t][row]

    // max(cache_len) once per block
    int mv = clen[lane & 31];
#pragma unroll
    for (int off = 16; off >= 1; off >>= 1) {
        int o = __shfl_xor(mv, off);
        mv = mv > o ? mv : o;
    }

    const int nItems = Bn * Hn * NCHUNK; // 32768
    for (int widx = blockIdx.x; widx < nItems; widx += PERSIST) {
        const int h = widx & (Hn - 1);
        const int bc = widx >> 4;
        const int cq = bc & (NCHUNK - 1);
        const int b = bc >> 6;
        const int cl = clen[b];
        if (cq != 0 && cq * CHUNK >= cl) continue;
        const int nv = min(max(cl - cq * CHUNK, 0), CHUNK);

        const size_t gb = ((size_t)b * Sn + (size_t)cq * CHUNK) * Cn + (size_t)h * HDn;
        // K -> LDS, pre-swizzled global source (verified conflict-free read)
#pragma unroll
        for (int i = 0; i < 16; ++i) {
            const int row = i * 4 + rg;
            gload_lds16(ck + gb + (size_t)row * Cn + (slot ^ (row & 15)) * 4, &K_l[i * 4][0]);
        }
        const float* vb = cv + gb + lane;
        // V quarter 0 (rows 0-15) -> registers, coalesced 256B rows
        float vq0[16];
#pragma unroll
        for (int r = 0; r < 16; ++r) vq0[r] = vb[(size_t)r * Cn];

        // wait K resident (the 16 newest outstanding = vq0; K + prior stores older)
        asm volatile("s_waitcnt vmcnt(16)" ::: "memory");
        __builtin_amdgcn_sched_barrier(0);

        // ---- QK: lane = row; K from LDS (conflict-free), q via uniform loads
        const float* qb = q + (size_t)b * Tn * Cn + (size_t)h * HDn;
        float s[8];
#pragma unroll
        for (int t = 0; t < 8; ++t) s[t] = 0.f;
#pragma unroll
        for (int dg = 0; dg < 16; ++dg) {
            const float4 kv = *(const float4*)&K_l[lane][(dg ^ swz) * 4];
#pragma unroll
            for (int t = 0; t < 8; ++t) {
                const float4 qv = *(const float4*)(qb + (size_t)t * Cn + dg * 4); // uniform
                s[t] += kv.x * qv.x + kv.y * qv.y + kv.z * qv.z + kv.w * qv.w;
            }
        }
        const bool val = lane < nv;
        float lden[8];
#pragma unroll
        for (int t = 0; t < 8; ++t) {
            const float p = val ? __expf(s[t]) : 0.f;
            lden[t] = p;
            p_l[t][lane] = p; // in-wave RAW; lgkmcnt auto
        }

        // ---- PV: lane = d; V register quarters, software-pipelined
        float av[8];
#pragma unroll
        for (int t = 0; t < 8; ++t) av[t] = 0.f;

#define PVQ(VQ, BASE)                                                         \
    do {                                                                      \
        _Pragma("unroll")                                                     \
        for (int r4 = 0; r4 < 4; ++r4) {                                      \
            float4 pt[8];                                                     \
            _Pragma("unroll")                                                 \
            for (int t = 0; t < 8; ++t)                                       \
                pt[t] = *(const float4*)&p_l[t][(BASE) + r4 * 4];             \
            _Pragma("unroll")                                                 \
            for (int u = 0; u < 4; ++u) {                                     \
                const float v = VQ[r4 * 4 + u];                               \
                _Pragma("unroll")                                             \
                for (int t = 0; t < 8; ++t) {                                 \
                    const float pu = (u == 0) ? pt[t].x                       \
                                   : (u == 1) ? pt[t].y                       \
                                   : (u == 2) ? pt[t].z : pt[t].w;            \
                    av[t] += pu * v;                                          \
                }                                                             \
            }                                                                 \
        }                                                                     \
    } while (0)

        float vq1[16];
#pragma unroll
        for (int r = 0; r < 16; ++r) vq1[r] = vb[(size_t)(16 + r) * Cn];
        PVQ(vq0, 0);
        float vq2[16];
#pragma unroll
        for (int r = 0; r < 16; ++r) vq2[r] = vb[(size_t)(32 + r) * Cn];
        PVQ(vq1, 16);
        float vq3[16];
#pragma unroll
        for (int r = 0; r < 16; ++r) vq3[r] = vb[(size_t)(48 + r) * Cn];
        PVQ(vq2, 32);
        PVQ(vq3, 48);
#undef PVQ

        // ---- new keys (8 rows): cq==0 items only
        if (cq == 0) {
            const int r = lane >> 3, dgrp = lane & 7; // lanes span cols: coalesced
            const float* kb = kn + ((size_t)b * Tn + r) * Cn + (size_t)h * HDn + dgrp * 8;
            const float4 ka = *(const float4*)(kb);
            const float4 kc = *(const float4*)(kb + 4);
            float sn[8];
#pragma unroll
            for (int t = 0; t < 8; ++t) {
                const float4 qa = *(const float4*)(qb + (size_t)t * Cn + dgrp * 8);
                const float4 qc = *(const float4*)(qb + (size_t)t * Cn + dgrp * 8 + 4);
                float v = ka.x * qa.x + ka.y * qa.y + ka.z * qa.z + ka.w * qa.w +
                          kc.x * qc.x + kc.y * qc.y + kc.z * qc.z + kc.w * qc.w;
                v += __shfl_xor(v, 1);
                v += __shfl_xor(v, 2);
                v += __shfl_xor(v, 4);
                sn[t] = v;
            }
            if (dgrp == 0) { // lanes 8r hold full sums for row r
#pragma unroll
                for (int t = 0; t < 8; ++t) {
                    const float p = __expf(sn[t]);
                    p_l[t][r] = p;
                    lden[t] += p;
                }
            }
            const float* vb2 = vn + (size_t)b * Tn * Cn + (size_t)h * HDn + lane;
#pragma unroll
            for (int r2 = 0; r2 < 8; ++r2) {
                const float v = vb2[(size_t)r2 * Cn];
#pragma unroll
                for (int t = 0; t < 8; ++t) av[t] += p_l[t][r2] * v;
            }
        }

        // lden: 64-lane butterfly; + zero-pad count (cq==0)
#pragma unroll
        for (int t = 0; t < 8; ++t) {
            float v = lden[t];
#pragma unroll
            for (int off = 32; off >= 1; off >>= 1) v += __shfl_xor(v, off);
            lden[t] = v;
        }
        if (cq == 0) {
            const float pad = (float)(mv - cl);
#pragma unroll
            for (int t = 0; t < 8; ++t) lden[t] += pad;
        }

        const size_t obase = (size_t)((cq * Bn + b) * Hn + h);
#pragma unroll
        for (int t = 0; t < 8; ++t) pacc[obase * 512 + (size_t)t * 64 + lane] = av[t];
        if (lane == 0) {
#pragma unroll
            for (int t = 0; t < 8; ++t) pl[obase * 8 + t] = lden[t];
        }
    }
}

// ---------------- Merge chunk partials, normalize (4-wave) ----------------
__global__ __launch_bounds__(256) void attn_merge_kernel(
    const float* __restrict__ pacc, const float* __restrict__ pl,
    const int* __restrict__ clen, float* __restrict__ aw) {
    const int h = blockIdx.x, b = blockIdx.y;
    const int tid = threadIdx.x, wave = tid >> 6, lane = tid & 63;
    const int cl = clen[b];
    int nch = (cl + CHUNK - 1) / CHUNK;
    if (nch < 1) nch = 1;

    __shared__ float racc[4][8][64];
    __shared__ float rl[4][8];

    float acc[8], l[8];
#pragma unroll
    for (int t = 0; t < 8; ++t) { acc[t] = 0.f; l[t] = 0.f; }
    for (int c = wave; c < nch; c += 4) {
        const size_t base = (size_t)((c * Bn + b) * Hn + h);
#pragma unroll
        for (int t = 0; t < 8; ++t) acc[t] += pacc[base * 512 + t * 64 + lane];
#pragma unroll
        for (int t = 0; t < 8; ++t) l[t] += pl[base * 8 + t];
    }
#pragma unroll
    for (int t = 0; t < 8; ++t) racc[wave][t][lane] = acc[t];
    if (lane == 0) {
#pragma unroll
        for (int t = 0; t < 8; ++t) rl[wave][t] = l[t];
    }
    __syncthreads();
#pragma unroll
    for (int rep = 0; rep < 2; ++rep) {
        const int e = rep * 256 + tid;
        const int t = e >> 6, d = e & 63;
        const float a = racc[0][t][d] + racc[1][t][d] + racc[2][t][d] + racc[3][t][d];
        const float ll = rl[0][t] + rl[1][t] + rl[2][t] + rl[3][t];
        aw[(size_t)(b * Tn + t) * Cn + (size_t)h * HDn + d] = a / ll;
    }
}

// ---------------- Sum final-GEMM partials + bias ----------------
__global__ __launch_bounds__(256) void bias_out_kernel(
    const float* __restrict__ opart, const float* __restrict__ bo, float* __restrict__ out) {
    const int f4 = blockIdx.x * 256 + threadIdx.x; // 65536 float4s
    const float4 a0 = *(const float4*)(opart + (size_t)f4 * 4);
    const float4 a1 = *(const float4*)(opart + PROJ_PART + (size_t)f4 * 4);
    const float4 a2 = *(const float4*)(opart + 2 * PROJ_PART + (size_t)f4 * 4);
    const float4 a3 = *(const float4*)(opart + 3 * PROJ_PART + (size_t)f4 * 4);
    const float4 bv = *(const float4*)&bo[(f4 & 255) * 4];
    float4 o = make_float4(a0.x + a1.x + a2.x + a3.x + bv.x,
                           a0.y + a1.y + a2.y + a3.y + bv.y,
                           a0.z + a1.z + a2.z + a3.z + bv.z,
                           a0.w + a1.w + a2.w + a3.w + bv.w);
    *(float4*)&out[(size_t)f4 * 4] = o;
}

extern "C" void kernel_launch(void* const* d_in, const int* in_sizes, int n_in,
                              void* d_out, int out_size, void* d_ws, size_t ws_size,
                              hipStream_t stream) {
    const float* x  = (const float*)d_in[0];
    const float* ck = (const float*)d_in[1];
    const float* cv = (const float*)d_in[2];
    const int*   cl = (const int*)d_in[3];
    const float* wq = (const float*)d_in[4];
    const float* wk = (const float*)d_in[5];
    const float* wv = (const float*)d_in[6];
    const float* wo = (const float*)d_in[7];
    const float* bo = (const float*)d_in[8];
    float* out = (float*)d_out;
    float* ws = (float*)d_ws;

    float* qpart = ws + QP_OFF;
    float* kpart = ws + KP_OFF;
    float* vpart = ws + VP_OFF;
    float* pacc  = ws + PACC_OFF;
    float* pl    = ws + PL_OFF;
    float* aw    = ws + AW_OFF;
    float* opart = ws + OP_OFF;
    float* qr    = ws + QR_OFF;
    float* knew  = ws + KN_OFF;
    float* vnew  = ws + VN_OFF;

    // 1) q/k/v projections (K-split-4 partials)
    proj3_kernel<<<dim3(16, 4, 12), dim3(256), 0, stream>>>(x, wq, wk, wv, qpart, kpart, vpart);
    // 1b) reduce partials -> q (pre-scaled), k_new, v_new
    prereduce_kernel<<<dim3(256), dim3(256), 0, stream>>>(qpart, kpart, vpart, qr, knew, vnew);
    // 2) attention partials: persistent 1-wave blocks
    attn_kernel<<<dim3(PERSIST), dim3(64), 0, stream>>>(qr, knew, vnew, ck, cv, cl, pacc, pl);
    // 3) merge + normalize (4-wave)
    attn_merge_kernel<<<dim3(Hn, Bn), dim3(256), 0, stream>>>(pacc, pl, cl, aw);
    // 4) output projection (K-split-4 partials)
    gemm1_kernel<<<dim3(16, 4, KSPLIT), dim3(256), 0, stream>>>(aw, wo, opart);
    // 5) sum partials + bias
    bias_out_kernel<<<dim3(256), dim3(256), 0, stream>>>(opart, bo, out);
}

// Round 10
// 204.126 us; speedup vs baseline: 1.5716x; 1.5716x over previous
//
#include <hip/hip_runtime.h>

// Problem constants
constexpr int Bn = 32, Tn = 8, Cn = 1024, Sn = 4096, Hn = 16, HDn = 64;
constexpr int CHUNK = 64, NCHUNK = 64;  // keys per attn block (1 wave per block)
constexpr int KSPLIT = 4;               // K-split for the 256x1024x1024 GEMMs
constexpr float SCALE = 0.125f;         // 1/sqrt(64)

// Workspace layout (in floats)
constexpr size_t PROJ_PART = (size_t)Bn * Tn * Cn;          // 262144
constexpr size_t QP_OFF = 0;
constexpr size_t KP_OFF = QP_OFF + KSPLIT * PROJ_PART;
constexpr size_t VP_OFF = KP_OFF + KSPLIT * PROJ_PART;
constexpr size_t PACC_OFF = VP_OFF + KSPLIT * PROJ_PART;
constexpr size_t PACC_SZ = (size_t)NCHUNK * Bn * Hn * Tn * HDn;  // 16.8M floats
constexpr size_t PL_OFF = PACC_OFF + PACC_SZ;
constexpr size_t PL_SZ = (size_t)NCHUNK * Bn * Hn * Tn;
constexpr size_t AW_OFF = PL_OFF + PL_SZ;
constexpr size_t AW_SZ = PROJ_PART;
constexpr size_t OP_OFF = AW_OFF + AW_SZ;
constexpr size_t OP_SZ = (size_t)KSPLIT * PROJ_PART;
constexpr size_t QR_OFF = OP_OFF + OP_SZ;                   // reduced q (pre-scaled)
constexpr size_t KN_OFF = QR_OFF + PROJ_PART;               // reduced k_new
constexpr size_t VN_OFF = KN_OFF + PROJ_PART;               // reduced v_new

typedef __attribute__((address_space(3))) unsigned int lds_uint;
typedef const __attribute__((address_space(1))) unsigned int glb_uint;

__device__ __forceinline__ void gload_lds16(const float* g, float* l) {
    __builtin_amdgcn_global_load_lds((glb_uint*)g, (lds_uint*)l, 16, 0, 0);
}

// ---------------- GEMM: Y_partial[sigma] = X(256xK-slice) @ W^T ----------------
__device__ __forceinline__ void gemm_body(const float* __restrict__ X,
                                          const float* __restrict__ W,
                                          float* __restrict__ Opart,
                                          int sigma, int jblk, int iblk) {
    __shared__ float wl[64][68]; // [k][j], pad 68
    const int tid = threadIdx.x;
    const int c = tid & 15, a = tid >> 4;
    const int j0 = jblk * 64;
    const int ib = iblk * 64 + a * 4;
    const int k0 = sigma * 256;

    float acc[4][4];
#pragma unroll
    for (int ii = 0; ii < 4; ++ii)
#pragma unroll
        for (int jj = 0; jj < 4; ++jj) acc[ii][jj] = 0.f;

    for (int kt = 0; kt < 4; ++kt) {
        const int k1 = k0 + kt * 64;
#pragma unroll
        for (int stp = 0; stp < 4; ++stp) {
            int f4 = stp * 256 + tid;
            int jr = f4 >> 4, e4 = f4 & 15;
            float4 wv = *(const float4*)&W[(size_t)(j0 + jr) * Cn + k1 + e4 * 4];
            wl[e4 * 4 + 0][jr] = wv.x;
            wl[e4 * 4 + 1][jr] = wv.y;
            wl[e4 * 4 + 2][jr] = wv.z;
            wl[e4 * 4 + 3][jr] = wv.w;
        }
        __syncthreads();
#pragma unroll 4
        for (int k4 = 0; k4 < 16; ++k4) {
            float4 xv[4];
#pragma unroll
            for (int ii = 0; ii < 4; ++ii)
                xv[ii] = *(const float4*)&X[(size_t)(ib + ii) * Cn + k1 + k4 * 4];
#pragma unroll
            for (int kk = 0; kk < 4; ++kk) {
                float4 wv = *(const float4*)&wl[k4 * 4 + kk][c * 4];
#pragma unroll
                for (int ii = 0; ii < 4; ++ii) {
                    const float xs = (kk == 0) ? xv[ii].x : (kk == 1) ? xv[ii].y
                                   : (kk == 2) ? xv[ii].z : xv[ii].w;
                    acc[ii][0] += xs * wv.x;
                    acc[ii][1] += xs * wv.y;
                    acc[ii][2] += xs * wv.z;
                    acc[ii][3] += xs * wv.w;
                }
            }
        }
        __syncthreads();
    }
    float* op = Opart + (size_t)sigma * PROJ_PART;
#pragma unroll
    for (int ii = 0; ii < 4; ++ii) {
        float4 o = make_float4(acc[ii][0], acc[ii][1], acc[ii][2], acc[ii][3]);
        *(float4*)&op[(size_t)(ib + ii) * Cn + j0 + c * 4] = o;
    }
}

__global__ __launch_bounds__(256) void proj3_kernel(
    const float* __restrict__ X, const float* __restrict__ W0,
    const float* __restrict__ W1, const float* __restrict__ W2,
    float* __restrict__ O0, float* __restrict__ O1, float* __restrict__ O2) {
    const int z = blockIdx.z;
    const float* W = (z < 4) ? W0 : (z < 8 ? W1 : W2);
    float* O = (z < 4) ? O0 : (z < 8 ? O1 : O2);
    gemm_body(X, W, O, z & 3, blockIdx.x, blockIdx.y);
}

__global__ __launch_bounds__(256) void gemm1_kernel(
    const float* __restrict__ X, const float* __restrict__ W, float* __restrict__ O) {
    gemm_body(X, W, O, blockIdx.z, blockIdx.x, blockIdx.y);
}

// ---------------- Pre-reduce K-split partials -> q (scaled), k_new, v_new ------
__global__ __launch_bounds__(256) void prereduce_kernel(
    const float* __restrict__ qp, const float* __restrict__ kp,
    const float* __restrict__ vp, float* __restrict__ q,
    float* __restrict__ kn, float* __restrict__ vn) {
    const size_t i = ((size_t)blockIdx.x * 256 + threadIdx.x) * 4;
#define SUM4(P)                                                              \
    make_float4(                                                             \
        (*(const float4*)(P + i)).x + (*(const float4*)(P + PROJ_PART + i)).x + \
        (*(const float4*)(P + 2 * PROJ_PART + i)).x + (*(const float4*)(P + 3 * PROJ_PART + i)).x, \
        (*(const float4*)(P + i)).y + (*(const float4*)(P + PROJ_PART + i)).y + \
        (*(const float4*)(P + 2 * PROJ_PART + i)).y + (*(const float4*)(P + 3 * PROJ_PART + i)).y, \
        (*(const float4*)(P + i)).z + (*(const float4*)(P + PROJ_PART + i)).z + \
        (*(const float4*)(P + 2 * PROJ_PART + i)).z + (*(const float4*)(P + 3 * PROJ_PART + i)).z, \
        (*(const float4*)(P + i)).w + (*(const float4*)(P + PROJ_PART + i)).w + \
        (*(const float4*)(P + 2 * PROJ_PART + i)).w + (*(const float4*)(P + 3 * PROJ_PART + i)).w)
    float4 qv = SUM4(qp);
    qv.x *= SCALE; qv.y *= SCALE; qv.z *= SCALE; qv.w *= SCALE;
    *(float4*)&q[i] = qv;
    *(float4*)&kn[i] = SUM4(kp);
    *(float4*)&vn[i] = SUM4(vp);
#undef SUM4
}

// ---------------- Attention partials: 1-wave blocks, V in registers ------------
// Grid (h=16, cq=64, b=32) = 32768 independent 1-wave blocks (R8 skeleton —
// natural dispatch balances the ragged lengths; R9's persistence broke this).
// Per block: q (2) + K (16, pre-swizzled source) via global_load_lds, then V
// quarter-0 to registers; vmcnt(16) -> K/q resident while V streams; QK from
// LDS (conflict-free); PV over 16-row register quarters with next-quarter
// prefetch. LDS 20 KB -> 8 blocks/CU = 2 waves/SIMD. No barriers.
__global__ __launch_bounds__(64) void attn_kernel(
    const float* __restrict__ q, const float* __restrict__ kn,
    const float* __restrict__ vn, const float* __restrict__ ck,
    const float* __restrict__ cv, const int* __restrict__ clen,
    float* __restrict__ pacc, float* __restrict__ pl) {
    const int h = blockIdx.x, cq = blockIdx.y, b = blockIdx.z;
    const int cl = clen[b];
    if (cq != 0 && cq * CHUNK >= cl) return; // uniform early exit

    const int lane = threadIdx.x;
    const int rg = lane >> 4;   // row-in-group 0..3
    const int slot = lane & 15; // 16B column group
    const int swz = lane & 15;

    __shared__ float K_l[64][64]; // 16 KB, XOR-swizzled slots
    __shared__ float q_l[8][64];  // 2 KB
    __shared__ float p_l[8][64];  // 2 KB, [t][row]

    // max(cache_len): load early so it retires before the DMA cluster
    int mv = clen[lane & 31];
#pragma unroll
    for (int off = 16; off >= 1; off >>= 1) {
        int o = __shfl_xor(mv, off);
        mv = mv > o ? mv : o;
    }

    // stage q (2 instr) + K (16 instr, pre-swizzled source)
    {
        const float* qb0 = q + (size_t)b * Tn * Cn + (size_t)h * HDn;
#pragma unroll
        for (int i = 0; i < 2; ++i) {
            const int row = i * 4 + rg;
            gload_lds16(qb0 + (size_t)row * Cn + slot * 4, &q_l[i * 4][0]);
        }
    }
    const size_t gb = ((size_t)b * Sn + (size_t)cq * CHUNK) * Cn + (size_t)h * HDn;
#pragma unroll
    for (int i = 0; i < 16; ++i) {
        const int row = i * 4 + rg;
        gload_lds16(ck + gb + (size_t)row * Cn + (slot ^ (row & 15)) * 4, &K_l[i * 4][0]);
    }
    __builtin_amdgcn_sched_barrier(0); // keep V loads AFTER the gload cluster
    // V quarter 0 (rows 0-15) -> registers, coalesced 256B rows
    const float* vb = cv + gb + lane;
    float vq0[16];
#pragma unroll
    for (int r = 0; r < 16; ++r) vq0[r] = vb[(size_t)r * Cn];
    __builtin_amdgcn_sched_barrier(0);

    const int nv = min(max(cl - cq * CHUNK, 0), CHUNK);

    // wait q+K resident; the 16 newest outstanding (vq0) may still fly
    asm volatile("s_waitcnt vmcnt(16)" ::: "memory");
    __builtin_amdgcn_sched_barrier(0);

    // ---- QK: lane = row; conflict-free swizzled b128 K reads, q broadcasts
    float s[8];
#pragma unroll
    for (int t = 0; t < 8; ++t) s[t] = 0.f;
#pragma unroll
    for (int dg = 0; dg < 16; ++dg) {
        const float4 kv = *(const float4*)&K_l[lane][(dg ^ swz) * 4];
#pragma unroll
        for (int t = 0; t < 8; ++t) {
            const float4 qv = *(const float4*)&q_l[t][dg * 4];
            s[t] += kv.x * qv.x + kv.y * qv.y + kv.z * qv.z + kv.w * qv.w;
        }
    }
    const bool val = lane < nv;
    float lden[8];
#pragma unroll
    for (int t = 0; t < 8; ++t) {
        const float p = val ? __expf(s[t]) : 0.f;
        lden[t] = p;
        p_l[t][lane] = p; // in-wave RAW; lgkmcnt auto
    }

    // ---- PV: lane = d; register V quarters, software-pipelined
    float av[8];
#pragma unroll
    for (int t = 0; t < 8; ++t) av[t] = 0.f;

#define PVQ(VQ, BASE)                                                         \
    do {                                                                      \
        _Pragma("unroll")                                                     \
        for (int r4 = 0; r4 < 4; ++r4) {                                      \
            float4 pt[8];                                                     \
            _Pragma("unroll")                                                 \
            for (int t = 0; t < 8; ++t)                                       \
                pt[t] = *(const float4*)&p_l[t][(BASE) + r4 * 4];             \
            _Pragma("unroll")                                                 \
            for (int u = 0; u < 4; ++u) {                                     \
                const float v = VQ[r4 * 4 + u];                               \
                _Pragma("unroll")                                             \
                for (int t = 0; t < 8; ++t) {                                 \
                    const float pu = (u == 0) ? pt[t].x                       \
                                   : (u == 1) ? pt[t].y                       \
                                   : (u == 2) ? pt[t].z : pt[t].w;            \
                    av[t] += pu * v;                                          \
                }                                                             \
            }                                                                 \
        }                                                                     \
    } while (0)

    float vq1[16];
#pragma unroll
    for (int r = 0; r < 16; ++r) vq1[r] = vb[(size_t)(16 + r) * Cn];
    PVQ(vq0, 0);
    float vq2[16];
#pragma unroll
    for (int r = 0; r < 16; ++r) vq2[r] = vb[(size_t)(32 + r) * Cn];
    PVQ(vq1, 16);
    float vq3[16];
#pragma unroll
    for (int r = 0; r < 16; ++r) vq3[r] = vb[(size_t)(48 + r) * Cn];
    PVQ(vq2, 32);
    PVQ(vq3, 48);
#undef PVQ

    // ---- new keys (8 rows): cq==0 only
    if (cq == 0) {
        const int r = lane >> 3, dgrp = lane & 7; // lanes span cols: coalesced
        const float* kb = kn + ((size_t)b * Tn + r) * Cn + (size_t)h * HDn + dgrp * 8;
        const float4 ka = *(const float4*)(kb);
        const float4 kc = *(const float4*)(kb + 4);
        float sn[8];
#pragma unroll
        for (int t = 0; t < 8; ++t) {
            const float4 qa = *(const float4*)&q_l[t][dgrp * 8];
            const float4 qc = *(const float4*)&q_l[t][dgrp * 8 + 4];
            float v = ka.x * qa.x + ka.y * qa.y + ka.z * qa.z + ka.w * qa.w +
                      kc.x * qc.x + kc.y * qc.y + kc.z * qc.z + kc.w * qc.w;
            v += __shfl_xor(v, 1);
            v += __shfl_xor(v, 2);
            v += __shfl_xor(v, 4);
            sn[t] = v;
        }
        if (dgrp == 0) { // lanes 8r hold full sums for row r
#pragma unroll
            for (int t = 0; t < 8; ++t) {
                const float p = __expf(sn[t]);
                p_l[t][r] = p;
                lden[t] += p;
            }
        }
        const float* vb2 = vn + (size_t)b * Tn * Cn + (size_t)h * HDn + lane;
#pragma unroll
        for (int r2 = 0; r2 < 8; ++r2) {
            const float v = vb2[(size_t)r2 * Cn];
#pragma unroll
            for (int t = 0; t < 8; ++t) av[t] += p_l[t][r2] * v;
        }
    }

    // lden: 64-lane butterfly; + zero-pad count (cq==0)
#pragma unroll
    for (int t = 0; t < 8; ++t) {
        float v = lden[t];
#pragma unroll
        for (int off = 32; off >= 1; off >>= 1) v += __shfl_xor(v, off);
        lden[t] = v;
    }
    if (cq == 0) {
        const float pad = (float)(mv - cl);
#pragma unroll
        for (int t = 0; t < 8; ++t) lden[t] += pad;
    }

    const size_t obase = (size_t)((cq * Bn + b) * Hn + h);
#pragma unroll
    for (int t = 0; t < 8; ++t) pacc[obase * 512 + (size_t)t * 64 + lane] = av[t];
    if (lane == 0) {
#pragma unroll
        for (int t = 0; t < 8; ++t) pl[obase * 8 + t] = lden[t];
    }
}

// ---------------- Merge chunk partials, normalize (4-wave) ----------------
__global__ __launch_bounds__(256) void attn_merge_kernel(
    const float* __restrict__ pacc, const float* __restrict__ pl,
    const int* __restrict__ clen, float* __restrict__ aw) {
    const int h = blockIdx.x, b = blockIdx.y;
    const int tid = threadIdx.x, wave = tid >> 6, lane = tid & 63;
    const int cl = clen[b];
    int nch = (cl + CHUNK - 1) / CHUNK;
    if (nch < 1) nch = 1;

    __shared__ float racc[4][8][64];
    __shared__ float rl[4][8];

    float acc[8], l[8];
#pragma unroll
    for (int t = 0; t < 8; ++t) { acc[t] = 0.f; l[t] = 0.f; }
    for (int c = wave; c < nch; c += 4) {
        const size_t base = (size_t)((c * Bn + b) * Hn + h);
#pragma unroll
        for (int t = 0; t < 8; ++t) acc[t] += pacc[base * 512 + t * 64 + lane];
#pragma unroll
        for (int t = 0; t < 8; ++t) l[t] += pl[base * 8 + t];
    }
#pragma unroll
    for (int t = 0; t < 8; ++t) racc[wave][t][lane] = acc[t];
    if (lane == 0) {
#pragma unroll
        for (int t = 0; t < 8; ++t) rl[wave][t] = l[t];
    }
    __syncthreads();
#pragma unroll
    for (int rep = 0; rep < 2; ++rep) {
        const int e = rep * 256 + tid;
        const int t = e >> 6, d = e & 63;
        const float a = racc[0][t][d] + racc[1][t][d] + racc[2][t][d] + racc[3][t][d];
        const float ll = rl[0][t] + rl[1][t] + rl[2][t] + rl[3][t];
        aw[(size_t)(b * Tn + t) * Cn + (size_t)h * HDn + d] = a / ll;
    }
}

// ---------------- Sum final-GEMM partials + bias ----------------
__global__ __launch_bounds__(256) void bias_out_kernel(
    const float* __restrict__ opart, const float* __restrict__ bo, float* __restrict__ out) {
    const int f4 = blockIdx.x * 256 + threadIdx.x; // 65536 float4s
    const float4 a0 = *(const float4*)(opart + (size_t)f4 * 4);
    const float4 a1 = *(const float4*)(opart + PROJ_PART + (size_t)f4 * 4);
    const float4 a2 = *(const float4*)(opart + 2 * PROJ_PART + (size_t)f4 * 4);
    const float4 a3 = *(const float4*)(opart + 3 * PROJ_PART + (size_t)f4 * 4);
    const float4 bv = *(const float4*)&bo[(f4 & 255) * 4];
    float4 o = make_float4(a0.x + a1.x + a2.x + a3.x + bv.x,
                           a0.y + a1.y + a2.y + a3.y + bv.y,
                           a0.z + a1.z + a2.z + a3.z + bv.z,
                           a0.w + a1.w + a2.w + a3.w + bv.w);
    *(float4*)&out[(size_t)f4 * 4] = o;
}

extern "C" void kernel_launch(void* const* d_in, const int* in_sizes, int n_in,
                              void* d_out, int out_size, void* d_ws, size_t ws_size,
                              hipStream_t stream) {
    const float* x  = (const float*)d_in[0];
    const float* ck = (const float*)d_in[1];
    const float* cv = (const float*)d_in[2];
    const int*   cl = (const int*)d_in[3];
    const float* wq = (const float*)d_in[4];
    const float* wk = (const float*)d_in[5];
    const float* wv = (const float*)d_in[6];
    const float* wo = (const float*)d_in[7];
    const float* bo = (const float*)d_in[8];
    float* out = (float*)d_out;
    float* ws = (float*)d_ws;

    float* qpart = ws + QP_OFF;
    float* kpart = ws + KP_OFF;
    float* vpart = ws + VP_OFF;
    float* pacc  = ws + PACC_OFF;
    float* pl    = ws + PL_OFF;
    float* aw    = ws + AW_OFF;
    float* opart = ws + OP_OFF;
    float* qr    = ws + QR_OFF;
    float* knew  = ws + KN_OFF;
    float* vnew  = ws + VN_OFF;

    // 1) q/k/v projections (K-split-4 partials)
    proj3_kernel<<<dim3(16, 4, 12), dim3(256), 0, stream>>>(x, wq, wk, wv, qpart, kpart, vpart);
    // 1b) reduce partials -> q (pre-scaled), k_new, v_new
    prereduce_kernel<<<dim3(256), dim3(256), 0, stream>>>(qpart, kpart, vpart, qr, knew, vnew);
    // 2) attention partials: 1-wave blocks, (head, chunk, batch)
    attn_kernel<<<dim3(Hn, NCHUNK, Bn), dim3(64), 0, stream>>>(qr, knew, vnew, ck, cv, cl, pacc, pl);
    // 3) merge + normalize (4-wave)
    attn_merge_kernel<<<dim3(Hn, Bn), dim3(256), 0, stream>>>(pacc, pl, cl, aw);
    // 4) output projection (K-split-4 partials)
    gemm1_kernel<<<dim3(16, 4, KSPLIT), dim3(256), 0, stream>>>(aw, wo, opart);
    // 5) sum partials + bias
    bias_out_kernel<<<dim3(256), dim3(256), 0, stream>>>(opart, bo, out);
}